// Round 4
// baseline (116.255 us; speedup 1.0000x reference)
//
#include <hip/hip_runtime.h>
#include <stdint.h>

#define NB 4
#define NC 256
#define NH 60
#define NW 80
#define NN (NH*NW)   // 4800

#define M_POS 1.0f
#define M_NEG 0.2f
#define THR2  64.0f  // THRESHOLD^2

typedef __attribute__((ext_vector_type(8))) short bf16x8;
typedef __attribute__((ext_vector_type(4))) float f32x4;

// ws layout (bytes):
//      0 : slots[256] float (partial accumulators)
//   1024 : Abf [B][N][C] bf16  (9830400 B)
// 9831424: Bbf [B][N][C] bf16  (9830400 B)
#define ABF_OFF 1024
#define BBF_OFF 9831424

__device__ __forceinline__ unsigned short f2bf(float f) {
  uint32_t u = __float_as_uint(f);
  uint32_t r = (u + 0x7FFFu + ((u >> 16) & 1u)) >> 16;  // RNE
  return (unsigned short)r;
}

// ---------------- transpose [C][N] f32 -> [N][C] bf16 ----------------
__global__ void tconv_kernel(const float* __restrict__ da, const float* __restrict__ db,
                             unsigned short* __restrict__ Abf, unsigned short* __restrict__ Bbf) {
  int t = blockIdx.x;              // 0..2399 = 2 tensors * 4 b * 4 ct * 75 nt
  int tensor = t / 1200; int rem = t % 1200;
  int b  = rem / 300;    int rem2 = rem % 300;
  int ct = rem2 / 75,    nt = rem2 % 75;
  int c0 = ct * 64, n0 = nt * 64;
  const float* in = (tensor ? db : da) + ((size_t)b * NC + c0) * NN + n0;
  unsigned short* out = (tensor ? Bbf : Abf) + ((size_t)b * NN + n0) * NC + c0;

  __shared__ float tile[64][65];
  int tr = threadIdx.x >> 6, tc = threadIdx.x & 63;
  #pragma unroll
  for (int i = 0; i < 16; ++i) {
    int c = i * 4 + tr;
    tile[c][tc] = in[(size_t)c * NN + tc];
  }
  __syncthreads();
  // write 2 consecutive bf16 along C as one dword
  int n_ = threadIdx.x >> 5;   // 0..7
  int c2 = threadIdx.x & 31;   // 0..31
  #pragma unroll
  for (int i = 0; i < 8; ++i) {
    int n = i * 8 + n_;
    uint32_t lo = f2bf(tile[c2 * 2][n]);
    uint32_t hi = f2bf(tile[c2 * 2 + 1][n]);
    *(uint32_t*)&out[(size_t)n * NC + c2 * 2] = lo | (hi << 16);
  }
}

// ---------------- fused GEMM + hinge(neg-branch) + reduce ----------------
// block tile 160(n) x 96(m), 4 waves (2x2), wave tile 80x48 = 5x3 frags 16x16x32
// K = 256 in 8 chunks of BK=32; static double-buffer, unrolled prefetch-1
#define BM 160
#define BN 96
#define BK 32

// 1024 16B-chunks per stage: 0..639 = A (160 rows x 4), 640..1023 = B (96 x 4)
// linear LDS dest; XOR-involution on global SOURCE: scol = col ^ ((row>>1)&3)
#define STAGE(kb, LA, LB) do {                                                        \
    _Pragma("unroll")                                                                 \
    for (int i_ = 0; i_ < 4; ++i_) {                                                  \
      int base_ = w * 256 + i_ * 64;                                                  \
      int cid_ = base_ + l;                                                           \
      if (base_ < 640) {                                                              \
        int row_ = cid_ >> 2, col_ = cid_ & 3;                                        \
        int scol_ = col_ ^ ((row_ >> 1) & 3);                                         \
        const unsigned short* g_ = Ab + (size_t)(n0 + row_) * NC + (kb) * BK + scol_ * 8; \
        __builtin_amdgcn_global_load_lds(                                             \
            (const __attribute__((address_space(1))) uint32_t*)g_,                    \
            (__attribute__((address_space(3))) uint32_t*)&LA[base_ * 8], 16, 0, 0);   \
      } else {                                                                        \
        int cid2_ = cid_ - 640;                                                       \
        int row_ = cid2_ >> 2, col_ = cid2_ & 3;                                      \
        int scol_ = col_ ^ ((row_ >> 1) & 3);                                         \
        const unsigned short* g_ = Bb + (size_t)(m0 + row_) * NC + (kb) * BK + scol_ * 8; \
        __builtin_amdgcn_global_load_lds(                                             \
            (const __attribute__((address_space(1))) uint32_t*)g_,                    \
            (__attribute__((address_space(3))) uint32_t*)&LB[(base_ - 640) * 8], 16, 0, 0); \
      }                                                                               \
    }                                                                                 \
  } while (0)

#define COMPUTE(LA, LB) do {                                                          \
    bf16x8 af_[5], bf_[3];                                                            \
    int c_ = l >> 4;                                                                  \
    _Pragma("unroll")                                                                 \
    for (int i_ = 0; i_ < 5; ++i_) {                                                  \
      int ra_ = wr * 80 + i_ * 16 + (l & 15);                                         \
      af_[i_] = *(const bf16x8*)&LA[ra_ * 32 + (c_ ^ ((ra_ >> 1) & 3)) * 8];          \
    }                                                                                 \
    _Pragma("unroll")                                                                 \
    for (int j_ = 0; j_ < 3; ++j_) {                                                  \
      int rb_ = wc * 48 + j_ * 16 + (l & 15);                                         \
      bf_[j_] = *(const bf16x8*)&LB[rb_ * 32 + (c_ ^ ((rb_ >> 1) & 3)) * 8];          \
    }                                                                                 \
    _Pragma("unroll")                                                                 \
    for (int i_ = 0; i_ < 5; ++i_)                                                    \
      _Pragma("unroll")                                                               \
      for (int j_ = 0; j_ < 3; ++j_)                                                  \
        acc[i_][j_] = __builtin_amdgcn_mfma_f32_16x16x32_bf16(af_[i_], bf_[j_],       \
                                                              acc[i_][j_], 0, 0, 0);  \
  } while (0)

__global__ __launch_bounds__(256) void gemm_loss_kernel(
    const unsigned short* __restrict__ Abf, const unsigned short* __restrict__ Bbf,
    float* __restrict__ slots) {
  __shared__ unsigned short la0[BM * BK], la1[BM * BK];
  __shared__ unsigned short lb0[BN * BK], lb1[BN * BK];
  __shared__ float red[4];

  // XCD-aware bijective swizzle: 6000 % 8 == 0
  int bid = blockIdx.x;
  int nb = (bid & 7) * 750 + (bid >> 3);
  int b = nb / 1500; int r = nb % 1500;
  int tn = r / 50, tm = r % 50;
  int n0 = tn * BM, m0 = tm * BN;

  int tid = threadIdx.x;
  int w = tid >> 6, l = tid & 63;
  int wr = w >> 1, wc = w & 1;

  const unsigned short* Ab = Abf + (size_t)b * NN * NC;
  const unsigned short* Bb = Bbf + (size_t)b * NN * NC;

  f32x4 acc[5][3];
  #pragma unroll
  for (int i = 0; i < 5; ++i)
    #pragma unroll
    for (int j = 0; j < 3; ++j)
      acc[i][j] = (f32x4){0.f, 0.f, 0.f, 0.f};

  STAGE(0, la0, lb0);
  __syncthreads();
  STAGE(1, la1, lb1); COMPUTE(la0, lb0); __syncthreads();
  STAGE(2, la0, lb0); COMPUTE(la1, lb1); __syncthreads();
  STAGE(3, la1, lb1); COMPUTE(la0, lb0); __syncthreads();
  STAGE(4, la0, lb0); COMPUTE(la1, lb1); __syncthreads();
  STAGE(5, la1, lb1); COMPUTE(la0, lb0); __syncthreads();
  STAGE(6, la0, lb0); COMPUTE(la1, lb1); __syncthreads();
  STAGE(7, la1, lb1); COMPUTE(la0, lb0); __syncthreads();
  COMPUTE(la1, lb1);

  // ---- epilogue: negative-branch hinge only (mask handled by corr_kernel)
  float lsum = 0.0f;
  #pragma unroll
  for (int i = 0; i < 5; ++i)
    #pragma unroll
    for (int j = 0; j < 3; ++j)
      #pragma unroll
      for (int q = 0; q < 4; ++q)
        lsum += fmaxf(acc[i][j][q] - M_NEG, 0.0f);

  #pragma unroll
  for (int off = 32; off > 0; off >>= 1)
    lsum += __shfl_xor(lsum, off);
  if (l == 0) red[w] = lsum;
  __syncthreads();
  if (tid == 0)
    atomicAdd(&slots[nb & 255], red[0] + red[1] + red[2] + red[3]);
}

// ---------------- sparse mask correction ----------------
// one wave per (b, n): warp center, test <=9 neighbor cells, for positives
// add relu(1-s) - relu(s-0.2) where s = bf16 dot over 256 channels
__global__ void corr_kernel(const unsigned short* __restrict__ Abf,
                            const unsigned short* __restrict__ Bbf,
                            const float* __restrict__ H, float* __restrict__ slots) {
  int gid = blockIdx.x * 4 + (threadIdx.x >> 6);   // 0..19199
  int l = threadIdx.x & 63;
  int b = gid / NN, n = gid % NN;
  int gi = n / NW, gj = n % NW;
  float x = gj * 8.0f + 4.0f, y = gi * 8.0f + 4.0f;
  const float* h = H + b * 9;
  float inv = 1.0f / (h[6] * x + h[7] * y + h[8]);
  float wx = (h[0] * x + h[1] * y + h[2]) * inv;
  float wy = (h[3] * x + h[4] * y + h[5]) * inv;

  const uint2 av = *(const uint2*)(Abf + (size_t)(b * NN + n) * NC + l * 4);
  float a0 = __uint_as_float(av.x << 16);
  float a1 = __uint_as_float(av.x & 0xffff0000u);
  float a2 = __uint_as_float(av.y << 16);
  float a3 = __uint_as_float(av.y & 0xffff0000u);

  int jc = (int)floorf((wx - 4.0f) * 0.125f + 0.5f);
  int ic = (int)floorf((wy - 4.0f) * 0.125f + 0.5f);

  float corr = 0.0f;
  #pragma unroll
  for (int di = -1; di <= 1; ++di) {
    #pragma unroll
    for (int dj = -1; dj <= 1; ++dj) {
      int im = ic + di, jm = jc + dj;
      if (im < 0 || im >= NH || jm < 0 || jm >= NW) continue;   // wave-uniform
      float cx = jm * 8.0f + 4.0f, cy = im * 8.0f + 4.0f;
      float dx = wx - cx, dy = wy - cy;
      if (dx * dx + dy * dy > THR2) continue;                    // wave-uniform
      const uint2 bv = *(const uint2*)(Bbf + (size_t)(b * NN + im * NW + jm) * NC + l * 4);
      float s = a0 * __uint_as_float(bv.x << 16)
              + a1 * __uint_as_float(bv.x & 0xffff0000u)
              + a2 * __uint_as_float(bv.y << 16)
              + a3 * __uint_as_float(bv.y & 0xffff0000u);
      #pragma unroll
      for (int off = 32; off > 0; off >>= 1)
        s += __shfl_xor(s, off);
      corr += fmaxf(M_POS - s, 0.0f) - fmaxf(s - M_NEG, 0.0f);
    }
  }
  if (l == 0) atomicAdd(&slots[gid & 255], corr);
}

__global__ void finalize_kernel(const float* __restrict__ slots, float* __restrict__ out) {
  float v = slots[threadIdx.x];                 // 256 threads, one slot each
  #pragma unroll
  for (int off = 32; off > 0; off >>= 1)
    v += __shfl_xor(v, off);
  __shared__ float red[4];
  if ((threadIdx.x & 63) == 0) red[threadIdx.x >> 6] = v;
  __syncthreads();
  if (threadIdx.x == 0)
    out[0] = (red[0] + red[1] + red[2] + red[3]) * (1.0f / ((float)NB * (float)NN * (float)NN));
}

extern "C" void kernel_launch(void* const* d_in, const int* in_sizes, int n_in,
                              void* d_out, int out_size, void* d_ws, size_t ws_size,
                              hipStream_t stream) {
  const float* da = (const float*)d_in[0];
  const float* db = (const float*)d_in[1];
  const float* H  = (const float*)d_in[2];
  // d_in[3] = valid_mask (all ones, unused by the reference math)

  char* ws = (char*)d_ws;
  float* slots = (float*)ws;
  unsigned short* Abf = (unsigned short*)(ws + ABF_OFF);
  unsigned short* Bbf = (unsigned short*)(ws + BBF_OFF);

  hipMemsetAsync(slots, 0, 1024, stream);
  tconv_kernel<<<2400, 256, 0, stream>>>(da, db, Abf, Bbf);
  gemm_loss_kernel<<<6000, 256, 0, stream>>>(Abf, Bbf, slots);
  corr_kernel<<<4800, 256, 0, stream>>>(Abf, Bbf, H, slots);
  finalize_kernel<<<1, 256, 0, stream>>>(slots, (float*)d_out);
}

// Round 5
// 115.667 us; speedup vs baseline: 1.0051x; 1.0051x over previous
//
#include <hip/hip_runtime.h>
#include <stdint.h>

#define NB 4
#define NC 256
#define NH 60
#define NW 80
#define NN (NH*NW)   // 4800

#define M_POS 1.0f
#define M_NEG 0.2f
#define THR2  64.0f  // THRESHOLD^2

typedef __attribute__((ext_vector_type(8))) short bf16x8;
typedef __attribute__((ext_vector_type(4))) float f32x4;

// ws layout (bytes):
//      0 : slots[256] float (partial accumulators)
//   1024 : Abf [B][N][C] bf16  (9830400 B)
// 9831424: Bbf [B][N][C] bf16  (9830400 B)
#define ABF_OFF 1024
#define BBF_OFF 9831424

__device__ __forceinline__ unsigned short f2bf(float f) {
  uint32_t u = __float_as_uint(f);
  uint32_t r = (u + 0x7FFFu + ((u >> 16) & 1u)) >> 16;  // RNE
  return (unsigned short)r;
}

// ---------------- transpose [C][N] f32 -> [N][C] bf16 (R3 pattern) ----------------
__global__ void tconv_kernel(const float* __restrict__ da, const float* __restrict__ db,
                             unsigned short* __restrict__ Abf, unsigned short* __restrict__ Bbf) {
  int t = blockIdx.x;              // 0..2399 = 2 tensors * 4 b * 4 ct * 75 nt
  int tensor = t / 1200; int rem = t % 1200;
  int b  = rem / 300;    int rem2 = rem % 300;
  int ct = rem2 / 75,    nt = rem2 % 75;
  int c0 = ct * 64, n0 = nt * 64;
  const float* in = (tensor ? db : da) + ((size_t)b * NC + c0) * NN + n0;
  unsigned short* out = (tensor ? Bbf : Abf) + ((size_t)b * NN + n0) * NC + c0;

  __shared__ float tile[64][65];
  int tr = threadIdx.x >> 6, tc = threadIdx.x & 63;
  #pragma unroll
  for (int i = 0; i < 16; ++i) {
    int c = i * 4 + tr;
    tile[c][tc] = in[(size_t)c * NN + tc];
  }
  __syncthreads();
  #pragma unroll
  for (int i = 0; i < 16; ++i) {
    int n = i * 4 + tr;
    out[(size_t)n * NC + tc] = f2bf(tile[tc][n]);
  }
}

// ---------------- fused GEMM + hinge(neg-branch) + reduce ----------------
// block tile 160(n) x 96(m), 4 waves (2x2), wave tile 80x48 = 5x3 frags 16x16x32
// K = 256 in 8 chunks of BK=32; THREE LDS buffers, counted vmcnt(4), 1 barrier/iter
#define BM 160
#define BN 96
#define BK 32

// 1024 16B-chunks per stage: 0..639 = A (160 rows x 4), 640..1023 = B (96 x 4)
// 4 global_load_lds per thread. linear LDS dest; XOR-involution on SOURCE.
#define STAGE(kb, LA, LB) do {                                                        \
    _Pragma("unroll")                                                                 \
    for (int i_ = 0; i_ < 4; ++i_) {                                                  \
      int base_ = w * 256 + i_ * 64;                                                  \
      int cid_ = base_ + l;                                                           \
      if (base_ < 640) {                                                              \
        int row_ = cid_ >> 2, col_ = cid_ & 3;                                        \
        int scol_ = col_ ^ ((row_ >> 1) & 3);                                         \
        const unsigned short* g_ = Ab + (size_t)(n0 + row_) * NC + (kb) * BK + scol_ * 8; \
        __builtin_amdgcn_global_load_lds(                                             \
            (const __attribute__((address_space(1))) uint32_t*)g_,                    \
            (__attribute__((address_space(3))) uint32_t*)&LA[base_ * 8], 16, 0, 0);   \
      } else {                                                                        \
        int cid2_ = cid_ - 640;                                                       \
        int row_ = cid2_ >> 2, col_ = cid2_ & 3;                                      \
        int scol_ = col_ ^ ((row_ >> 1) & 3);                                         \
        const unsigned short* g_ = Bb + (size_t)(m0 + row_) * NC + (kb) * BK + scol_ * 8; \
        __builtin_amdgcn_global_load_lds(                                             \
            (const __attribute__((address_space(1))) uint32_t*)g_,                    \
            (__attribute__((address_space(3))) uint32_t*)&LB[(base_ - 640) * 8], 16, 0, 0); \
      }                                                                               \
    }                                                                                 \
  } while (0)

#define COMPUTE(LA, LB) do {                                                          \
    bf16x8 af_[5], bf_[3];                                                            \
    int c_ = l >> 4;                                                                  \
    _Pragma("unroll")                                                                 \
    for (int i_ = 0; i_ < 5; ++i_) {                                                  \
      int ra_ = wr * 80 + i_ * 16 + (l & 15);                                         \
      af_[i_] = *(const bf16x8*)&LA[ra_ * 32 + (c_ ^ ((ra_ >> 1) & 3)) * 8];          \
    }                                                                                 \
    _Pragma("unroll")                                                                 \
    for (int j_ = 0; j_ < 3; ++j_) {                                                  \
      int rb_ = wc * 48 + j_ * 16 + (l & 15);                                         \
      bf_[j_] = *(const bf16x8*)&LB[rb_ * 32 + (c_ ^ ((rb_ >> 1) & 3)) * 8];          \
    }                                                                                 \
    _Pragma("unroll")                                                                 \
    for (int i_ = 0; i_ < 5; ++i_)                                                    \
      _Pragma("unroll")                                                               \
      for (int j_ = 0; j_ < 3; ++j_)                                                  \
        acc[i_][j_] = __builtin_amdgcn_mfma_f32_16x16x32_bf16(af_[i_], bf_[j_],       \
                                                              acc[i_][j_], 0, 0, 0);  \
  } while (0)

// counted-vmcnt wait + raw barrier; memory clobber + sched fence (rule #18)
#define WAITV_BAR(N) do {                                              \
    asm volatile("s_waitcnt vmcnt(" #N ")" ::: "memory");              \
    __builtin_amdgcn_sched_barrier(0);                                 \
    __builtin_amdgcn_s_barrier();                                      \
    __builtin_amdgcn_sched_barrier(0);                                 \
  } while (0)

__global__ __launch_bounds__(256) void gemm_loss_kernel(
    const unsigned short* __restrict__ Abf, const unsigned short* __restrict__ Bbf,
    float* __restrict__ slots) {
  __shared__ unsigned short la0[BM * BK], la1[BM * BK], la2[BM * BK];
  __shared__ unsigned short lb0[BN * BK], lb1[BN * BK], lb2[BN * BK];
  __shared__ float red[4];

  // XCD-aware bijective swizzle: 6000 % 8 == 0
  int bid = blockIdx.x;
  int nb = (bid & 7) * 750 + (bid >> 3);
  int b = nb / 1500; int r = nb % 1500;
  int tn = r / 50, tm = r % 50;
  int n0 = tn * BM, m0 = tm * BN;

  int tid = threadIdx.x;
  int w = tid >> 6, l = tid & 63;
  int wr = w >> 1, wc = w & 1;

  const unsigned short* Ab = Abf + (size_t)b * NN * NC;
  const unsigned short* Bb = Bbf + (size_t)b * NN * NC;

  f32x4 acc[5][3];
  #pragma unroll
  for (int i = 0; i < 5; ++i)
    #pragma unroll
    for (int j = 0; j < 3; ++j)
      acc[i][j] = (f32x4){0.f, 0.f, 0.f, 0.f};

  // prologue: 2 chunks in flight
  STAGE(0, la0, lb0);
  STAGE(1, la1, lb1);
  WAITV_BAR(4);                                    // chunk 0 landed (all waves)
  // rotation: stage(t+2) -> buf[(t+2)%3]; compute buf[t%3]; wait stage(t+1)
  STAGE(2, la2, lb2); COMPUTE(la0, lb0); WAITV_BAR(4);
  STAGE(3, la0, lb0); COMPUTE(la1, lb1); WAITV_BAR(4);
  STAGE(4, la1, lb1); COMPUTE(la2, lb2); WAITV_BAR(4);
  STAGE(5, la2, lb2); COMPUTE(la0, lb0); WAITV_BAR(4);
  STAGE(6, la0, lb0); COMPUTE(la1, lb1); WAITV_BAR(4);
  STAGE(7, la1, lb1); COMPUTE(la2, lb2); WAITV_BAR(4);
  COMPUTE(la0, lb0);  WAITV_BAR(0);                // drain chunk 7 (only once)
  COMPUTE(la1, lb1);

  // ---- epilogue: negative-branch hinge only (mask handled by corr_kernel)
  float lsum = 0.0f;
  #pragma unroll
  for (int i = 0; i < 5; ++i)
    #pragma unroll
    for (int j = 0; j < 3; ++j)
      #pragma unroll
      for (int q = 0; q < 4; ++q)
        lsum += fmaxf(acc[i][j][q] - M_NEG, 0.0f);

  #pragma unroll
  for (int off = 32; off > 0; off >>= 1)
    lsum += __shfl_xor(lsum, off);
  if (l == 0) red[w] = lsum;
  __syncthreads();
  if (tid == 0)
    atomicAdd(&slots[nb & 255], red[0] + red[1] + red[2] + red[3]);
}

// ---------------- sparse mask correction ----------------
// one wave per (b, n). The 4 cells surrounding the warped point are the only
// candidates with dist <= 8 (grid pitch 8). Issue all 4 loads independently,
// then 4 ILP-interleaved butterflies.
__global__ void corr_kernel(const unsigned short* __restrict__ Abf,
                            const unsigned short* __restrict__ Bbf,
                            const float* __restrict__ H, float* __restrict__ slots) {
  int gid = blockIdx.x * 4 + (threadIdx.x >> 6);   // 0..19199
  int l = threadIdx.x & 63;
  int b = gid / NN, n = gid % NN;
  int gi = n / NW, gj = n % NW;
  float x = gj * 8.0f + 4.0f, y = gi * 8.0f + 4.0f;
  const float* h = H + b * 9;
  float inv = 1.0f / (h[6] * x + h[7] * y + h[8]);
  float wx = (h[0] * x + h[1] * y + h[2]) * inv;
  float wy = (h[3] * x + h[4] * y + h[5]) * inv;

  const uint2 av = *(const uint2*)(Abf + (size_t)(b * NN + n) * NC + l * 4);
  float a0 = __uint_as_float(av.x << 16);
  float a1 = __uint_as_float(av.x & 0xffff0000u);
  float a2 = __uint_as_float(av.y << 16);
  float a3 = __uint_as_float(av.y & 0xffff0000u);

  // surrounding 2x2 cells (clamped to avoid int overflow; dist test rejects)
  float fy = fminf(fmaxf((wy - 4.0f) * 0.125f, -2.0f), (float)NH + 1.0f);
  float fx = fminf(fmaxf((wx - 4.0f) * 0.125f, -2.0f), (float)NW + 1.0f);
  int i0 = (int)floorf(fy), j0 = (int)floorf(fx);

  bool  val[4];
  float dot[4];
  #pragma unroll
  for (int c = 0; c < 4; ++c) {
    int im = i0 + (c >> 1), jm = j0 + (c & 1);
    float dx = wx - (jm * 8.0f + 4.0f);
    float dy = wy - (im * 8.0f + 4.0f);
    bool v = (im >= 0) & (im < NH) & (jm >= 0) & (jm < NW) &
             (dx * dx + dy * dy <= THR2);
    val[c] = v;
    int m = v ? (im * NW + jm) : 0;
    const uint2 bv = *(const uint2*)(Bbf + (size_t)(b * NN + m) * NC + l * 4);
    dot[c] = a0 * __uint_as_float(bv.x << 16)
           + a1 * __uint_as_float(bv.x & 0xffff0000u)
           + a2 * __uint_as_float(bv.y << 16)
           + a3 * __uint_as_float(bv.y & 0xffff0000u);
  }
  // 4 independent butterflies, interleaved for ILP
  #pragma unroll
  for (int off = 32; off > 0; off >>= 1) {
    dot[0] += __shfl_xor(dot[0], off);
    dot[1] += __shfl_xor(dot[1], off);
    dot[2] += __shfl_xor(dot[2], off);
    dot[3] += __shfl_xor(dot[3], off);
  }
  if (l == 0) {
    float corr = 0.0f;
    #pragma unroll
    for (int c = 0; c < 4; ++c)
      if (val[c])
        corr += fmaxf(M_POS - dot[c], 0.0f) - fmaxf(dot[c] - M_NEG, 0.0f);
    atomicAdd(&slots[gid & 255], corr);
  }
}

__global__ void finalize_kernel(const float* __restrict__ slots, float* __restrict__ out) {
  float v = slots[threadIdx.x];                 // 256 threads, one slot each
  #pragma unroll
  for (int off = 32; off > 0; off >>= 1)
    v += __shfl_xor(v, off);
  __shared__ float red[4];
  if ((threadIdx.x & 63) == 0) red[threadIdx.x >> 6] = v;
  __syncthreads();
  if (threadIdx.x == 0)
    out[0] = (red[0] + red[1] + red[2] + red[3]) * (1.0f / ((float)NB * (float)NN * (float)NN));
}

extern "C" void kernel_launch(void* const* d_in, const int* in_sizes, int n_in,
                              void* d_out, int out_size, void* d_ws, size_t ws_size,
                              hipStream_t stream) {
  const float* da = (const float*)d_in[0];
  const float* db = (const float*)d_in[1];
  const float* H  = (const float*)d_in[2];
  // d_in[3] = valid_mask (all ones, unused by the reference math)

  char* ws = (char*)d_ws;
  float* slots = (float*)ws;
  unsigned short* Abf = (unsigned short*)(ws + ABF_OFF);
  unsigned short* Bbf = (unsigned short*)(ws + BBF_OFF);

  hipMemsetAsync(slots, 0, 1024, stream);
  tconv_kernel<<<2400, 256, 0, stream>>>(da, db, Abf, Bbf);
  gemm_loss_kernel<<<6000, 256, 0, stream>>>(Abf, Bbf, slots);
  corr_kernel<<<4800, 256, 0, stream>>>(Abf, Bbf, H, slots);
  finalize_kernel<<<1, 256, 0, stream>>>(slots, (float*)d_out);
}

// Round 6
// 98.704 us; speedup vs baseline: 1.1778x; 1.1719x over previous
//
#include <hip/hip_runtime.h>
#include <stdint.h>

#define NB 4
#define NC 256
#define NH 60
#define NW 80
#define NN (NH*NW)   // 4800

#define M_POS 1.0f
#define M_NEG 0.2f
#define THR2  64.0f  // THRESHOLD^2

typedef __attribute__((ext_vector_type(8))) short bf16x8;
typedef __attribute__((ext_vector_type(4))) float f32x4;

// ws layout (bytes):
//      0 : gemmbuf[6000] float   (per-block partials, no atomics)
//  24000 : corrbuf[19200] float  (per-wave partials, no atomics)
// 102400 : Abf [B][N][C] bf16    (9830400 B)
// 9932800: Bbf [B][N][C] bf16    (9830400 B)
#define CORR_OFF 24000
#define ABF_OFF  102400
#define BBF_OFF  9932800
#define NPART    25200            // 6000 + 19200

__device__ __forceinline__ unsigned short f2bf(float f) {
  uint32_t u = __float_as_uint(f);
  uint32_t r = (u + 0x7FFFu + ((u >> 16) & 1u)) >> 16;  // RNE
  return (unsigned short)r;
}

// ---------------- transpose [C][N] f32 -> [N][C] bf16 ----------------
__global__ void tconv_kernel(const float* __restrict__ da, const float* __restrict__ db,
                             unsigned short* __restrict__ Abf, unsigned short* __restrict__ Bbf) {
  int t = blockIdx.x;              // 0..2399 = 2 tensors * 4 b * 4 ct * 75 nt
  int tensor = t / 1200; int rem = t % 1200;
  int b  = rem / 300;    int rem2 = rem % 300;
  int ct = rem2 / 75,    nt = rem2 % 75;
  int c0 = ct * 64, n0 = nt * 64;
  const float* in = (tensor ? db : da) + ((size_t)b * NC + c0) * NN + n0;
  unsigned short* out = (tensor ? Bbf : Abf) + ((size_t)b * NN + n0) * NC + c0;

  __shared__ float tile[64][65];
  int tr = threadIdx.x >> 6, tc = threadIdx.x & 63;
  #pragma unroll
  for (int i = 0; i < 16; ++i) {
    int c = i * 4 + tr;
    tile[c][tc] = in[(size_t)c * NN + tc];
  }
  __syncthreads();
  #pragma unroll
  for (int i = 0; i < 16; ++i) {
    int n = i * 4 + tr;
    out[(size_t)n * NC + tc] = f2bf(tile[tc][n]);
  }
}

// ---------------- fused GEMM + hinge(neg-branch) + reduce ----------------
// block tile 160(n) x 96(m), 4 waves (2x2), wave tile 80x48 = 5x3 frags 16x16x32
// K = 256 in 8 chunks of BK=32; 3 LDS buffers, counted vmcnt(4), 1 barrier/iter
// ALL addresses hoisted to the prologue; per-chunk K offset folds into the
// instruction's immediate (kb*BK shorts = kb*64B <= 448 < 4096).
#define BM 160
#define BN 96
#define BK 32

#define STAGE(kb, LA, LB) do {                                                        \
    _Pragma("unroll")                                                                 \
    for (int i_ = 0; i_ < 4; ++i_) {                                                  \
      if (inA_[i_])                                                                   \
        __builtin_amdgcn_global_load_lds(                                             \
            (const __attribute__((address_space(1))) uint32_t*)(gsrc_[i_] + (kb) * BK), \
            (__attribute__((address_space(3))) uint32_t*)(&LA[ldso_[i_]]), 16, 0, 0); \
      else                                                                            \
        __builtin_amdgcn_global_load_lds(                                             \
            (const __attribute__((address_space(1))) uint32_t*)(gsrc_[i_] + (kb) * BK), \
            (__attribute__((address_space(3))) uint32_t*)(&LB[ldso_[i_]]), 16, 0, 0); \
    }                                                                                 \
  } while (0)

#define COMPUTE(LA, LB) do {                                                          \
    bf16x8 af_[5], bf_[3];                                                            \
    _Pragma("unroll")                                                                 \
    for (int i_ = 0; i_ < 5; ++i_) af_[i_] = *(const bf16x8*)&LA[aoff_[i_]];          \
    _Pragma("unroll")                                                                 \
    for (int j_ = 0; j_ < 3; ++j_) bf_[j_] = *(const bf16x8*)&LB[boff_[j_]];          \
    _Pragma("unroll")                                                                 \
    for (int i_ = 0; i_ < 5; ++i_)                                                    \
      _Pragma("unroll")                                                               \
      for (int j_ = 0; j_ < 3; ++j_)                                                  \
        acc[i_][j_] = __builtin_amdgcn_mfma_f32_16x16x32_bf16(af_[i_], bf_[j_],       \
                                                              acc[i_][j_], 0, 0, 0);  \
  } while (0)

// counted-vmcnt wait + raw barrier; memory clobber + sched fence (rule #18)
#define WAITV_BAR(N) do {                                              \
    asm volatile("s_waitcnt vmcnt(" #N ")" ::: "memory");              \
    __builtin_amdgcn_sched_barrier(0);                                 \
    __builtin_amdgcn_s_barrier();                                      \
    __builtin_amdgcn_sched_barrier(0);                                 \
  } while (0)

__global__ __launch_bounds__(256, 3) void gemm_loss_kernel(
    const unsigned short* __restrict__ Abf, const unsigned short* __restrict__ Bbf,
    float* __restrict__ gemmbuf) {
  __shared__ unsigned short la0[BM * BK], la1[BM * BK], la2[BM * BK];
  __shared__ unsigned short lb0[BN * BK], lb1[BN * BK], lb2[BN * BK];
  __shared__ float red[4];

  // XCD-aware bijective swizzle: 6000 % 8 == 0
  int bid = blockIdx.x;
  int nb = (bid & 7) * 750 + (bid >> 3);
  int b = nb / 1500; int r = nb % 1500;
  int tn = r / 50, tm = r % 50;
  int n0 = tn * BM, m0 = tm * BN;

  int tid = threadIdx.x;
  int w = tid >> 6, l = tid & 63;
  int wr = w >> 1, wc = w & 1;

  const unsigned short* Ab = Abf + (size_t)b * NN * NC;
  const unsigned short* Bb = Bbf + (size_t)b * NN * NC;

  // ---- hoisted staging addresses (loop-invariant; kb folds to imm offset)
  // 1024 16B-chunks per stage: 0..639 = A (160 rows x 4), 640..1023 = B (96 x 4)
  // linear LDS dest; XOR-involution on global SOURCE: scol = col ^ ((row>>1)&3)
  bool inA_[4]; const unsigned short* gsrc_[4]; int ldso_[4];
  #pragma unroll
  for (int i = 0; i < 4; ++i) {
    int base = w * 256 + i * 64;
    int cid = base + l;
    if (base < 640) {
      int row = cid >> 2, col = cid & 3;
      int scol = col ^ ((row >> 1) & 3);
      inA_[i] = true;
      gsrc_[i] = Ab + (size_t)(n0 + row) * NC + scol * 8;
      ldso_[i] = base * 8;
    } else {
      int cid2 = cid - 640;
      int row = cid2 >> 2, col = cid2 & 3;
      int scol = col ^ ((row >> 1) & 3);
      inA_[i] = false;
      gsrc_[i] = Bb + (size_t)(m0 + row) * NC + scol * 8;
      ldso_[i] = (base - 640) * 8;
    }
  }
  // ---- hoisted LDS fragment offsets (same involution on READ)
  int aoff_[5], boff_[3];
  {
    int c_ = l >> 4;
    #pragma unroll
    for (int i = 0; i < 5; ++i) {
      int ra = wr * 80 + i * 16 + (l & 15);
      aoff_[i] = ra * 32 + (c_ ^ ((ra >> 1) & 3)) * 8;
    }
    #pragma unroll
    for (int j = 0; j < 3; ++j) {
      int rb = wc * 48 + j * 16 + (l & 15);
      boff_[j] = rb * 32 + (c_ ^ ((rb >> 1) & 3)) * 8;
    }
  }

  f32x4 acc[5][3];
  #pragma unroll
  for (int i = 0; i < 5; ++i)
    #pragma unroll
    for (int j = 0; j < 3; ++j)
      acc[i][j] = (f32x4){0.f, 0.f, 0.f, 0.f};

  // prologue: 2 chunks in flight
  STAGE(0, la0, lb0);
  STAGE(1, la1, lb1);
  WAITV_BAR(4);                                    // chunk 0 landed (all waves)
  STAGE(2, la2, lb2); COMPUTE(la0, lb0); WAITV_BAR(4);
  STAGE(3, la0, lb0); COMPUTE(la1, lb1); WAITV_BAR(4);
  STAGE(4, la1, lb1); COMPUTE(la2, lb2); WAITV_BAR(4);
  STAGE(5, la2, lb2); COMPUTE(la0, lb0); WAITV_BAR(4);
  STAGE(6, la0, lb0); COMPUTE(la1, lb1); WAITV_BAR(4);
  STAGE(7, la1, lb1); COMPUTE(la2, lb2); WAITV_BAR(4);
  COMPUTE(la0, lb0);  WAITV_BAR(0);                // drain chunk 7 (only once)
  COMPUTE(la1, lb1);

  // ---- epilogue: negative-branch hinge only (mask handled by corr_kernel)
  float lsum = 0.0f;
  #pragma unroll
  for (int i = 0; i < 5; ++i)
    #pragma unroll
    for (int j = 0; j < 3; ++j)
      #pragma unroll
      for (int q = 0; q < 4; ++q)
        lsum += fmaxf(acc[i][j][q] - M_NEG, 0.0f);

  #pragma unroll
  for (int off = 32; off > 0; off >>= 1)
    lsum += __shfl_xor(lsum, off);
  if (l == 0) red[w] = lsum;
  __syncthreads();
  if (tid == 0)
    gemmbuf[nb] = red[0] + red[1] + red[2] + red[3];   // plain store, no atomic
}

// ---------------- sparse mask correction ----------------
// one wave per (b, n); 4 surrounding cells are the only dist<=8 candidates.
// Per-wave partial written to corrbuf[gid] — NO atomics.
__global__ void corr_kernel(const unsigned short* __restrict__ Abf,
                            const unsigned short* __restrict__ Bbf,
                            const float* __restrict__ H, float* __restrict__ corrbuf) {
  int gid = blockIdx.x * 4 + (threadIdx.x >> 6);   // 0..19199
  int l = threadIdx.x & 63;
  int b = gid / NN, n = gid % NN;
  int gi = n / NW, gj = n % NW;
  float x = gj * 8.0f + 4.0f, y = gi * 8.0f + 4.0f;
  const float* h = H + b * 9;
  float inv = 1.0f / (h[6] * x + h[7] * y + h[8]);
  float wx = (h[0] * x + h[1] * y + h[2]) * inv;
  float wy = (h[3] * x + h[4] * y + h[5]) * inv;

  const uint2 av = *(const uint2*)(Abf + (size_t)(b * NN + n) * NC + l * 4);
  float a0 = __uint_as_float(av.x << 16);
  float a1 = __uint_as_float(av.x & 0xffff0000u);
  float a2 = __uint_as_float(av.y << 16);
  float a3 = __uint_as_float(av.y & 0xffff0000u);

  float fy = fminf(fmaxf((wy - 4.0f) * 0.125f, -2.0f), (float)NH + 1.0f);
  float fx = fminf(fmaxf((wx - 4.0f) * 0.125f, -2.0f), (float)NW + 1.0f);
  int i0 = (int)floorf(fy), j0 = (int)floorf(fx);

  bool  val[4];
  float dot[4];
  #pragma unroll
  for (int c = 0; c < 4; ++c) {
    int im = i0 + (c >> 1), jm = j0 + (c & 1);
    float dx = wx - (jm * 8.0f + 4.0f);
    float dy = wy - (im * 8.0f + 4.0f);
    bool v = (im >= 0) & (im < NH) & (jm >= 0) & (jm < NW) &
             (dx * dx + dy * dy <= THR2);
    val[c] = v;
    int m = v ? (im * NW + jm) : 0;
    const uint2 bv = *(const uint2*)(Bbf + (size_t)(b * NN + m) * NC + l * 4);
    dot[c] = a0 * __uint_as_float(bv.x << 16)
           + a1 * __uint_as_float(bv.x & 0xffff0000u)
           + a2 * __uint_as_float(bv.y << 16)
           + a3 * __uint_as_float(bv.y & 0xffff0000u);
  }
  #pragma unroll
  for (int off = 32; off > 0; off >>= 1) {
    dot[0] += __shfl_xor(dot[0], off);
    dot[1] += __shfl_xor(dot[1], off);
    dot[2] += __shfl_xor(dot[2], off);
    dot[3] += __shfl_xor(dot[3], off);
  }
  if (l == 0) {
    float corr = 0.0f;
    #pragma unroll
    for (int c = 0; c < 4; ++c)
      if (val[c])
        corr += fmaxf(M_POS - dot[c], 0.0f) - fmaxf(dot[c] - M_NEG, 0.0f);
    corrbuf[gid] = corr;                            // plain store, no atomic
  }
}

// ---------------- final reduction over all partials ----------------
__global__ void finalize_kernel(const float* __restrict__ parts, float* __restrict__ out) {
  float v = 0.0f;
  for (int i = threadIdx.x; i < NPART; i += 256)
    v += parts[i];
  #pragma unroll
  for (int off = 32; off > 0; off >>= 1)
    v += __shfl_xor(v, off);
  __shared__ float red[4];
  if ((threadIdx.x & 63) == 0) red[threadIdx.x >> 6] = v;
  __syncthreads();
  if (threadIdx.x == 0)
    out[0] = (red[0] + red[1] + red[2] + red[3]) * (1.0f / ((float)NB * (float)NN * (float)NN));
}

extern "C" void kernel_launch(void* const* d_in, const int* in_sizes, int n_in,
                              void* d_out, int out_size, void* d_ws, size_t ws_size,
                              hipStream_t stream) {
  const float* da = (const float*)d_in[0];
  const float* db = (const float*)d_in[1];
  const float* H  = (const float*)d_in[2];
  // d_in[3] = valid_mask (all ones, unused by the reference math)

  char* ws = (char*)d_ws;
  float* gemmbuf = (float*)ws;                    // 6000 floats
  float* corrbuf = (float*)(ws + CORR_OFF);       // 19200 floats
  unsigned short* Abf = (unsigned short*)(ws + ABF_OFF);
  unsigned short* Bbf = (unsigned short*)(ws + BBF_OFF);

  tconv_kernel<<<2400, 256, 0, stream>>>(da, db, Abf, Bbf);
  gemm_loss_kernel<<<6000, 256, 0, stream>>>(Abf, Bbf, gemmbuf);
  corr_kernel<<<4800, 256, 0, stream>>>(Abf, Bbf, H, corrbuf);
  finalize_kernel<<<1, 256, 0, stream>>>(gemmbuf, (float*)d_out);
}

// Round 7
// 77.704 us; speedup vs baseline: 1.4961x; 1.2703x over previous
//
#include <hip/hip_runtime.h>
#include <stdint.h>

#define NB 4
#define NC 256
#define NH 60
#define NW 80
#define NN (NH*NW)   // 4800

#define M_POS 1.0f
#define M_NEG 0.2f
#define THR2  64.0f  // THRESHOLD^2

typedef __attribute__((ext_vector_type(8))) short bf16x8;
typedef __attribute__((ext_vector_type(4))) float f32x4;

// ws layout (bytes):
//      0 : gemmbuf[6000] float   (per-block partials)
//  24000 : corrbuf[4800] float   (per-block partials)  -> contiguous NPART=10800
// 102400 : Abf [B][N][C] bf16    (9830400 B)
// 9932800: Bbf [B][N][C] bf16    (9830400 B)
#define CORR_OFF 24000
#define ABF_OFF  102400
#define BBF_OFF  9932800
#define NPART    10800            // 6000 + 4800

#define NGEMM 6000
#define NCORR 4800

__device__ __forceinline__ unsigned short f2bf(float f) {
  uint32_t u = __float_as_uint(f);
  uint32_t r = (u + 0x7FFFu + ((u >> 16) & 1u)) >> 16;  // RNE
  return (unsigned short)r;
}

// ---------------- transpose [C][N] f32 -> [N][C] bf16 ----------------
__global__ void tconv_kernel(const float* __restrict__ da, const float* __restrict__ db,
                             unsigned short* __restrict__ Abf, unsigned short* __restrict__ Bbf) {
  int t = blockIdx.x;              // 0..2399 = 2 tensors * 4 b * 4 ct * 75 nt
  int tensor = t / 1200; int rem = t % 1200;
  int b  = rem / 300;    int rem2 = rem % 300;
  int ct = rem2 / 75,    nt = rem2 % 75;
  int c0 = ct * 64, n0 = nt * 64;
  const float* in = (tensor ? db : da) + ((size_t)b * NC + c0) * NN + n0;
  unsigned short* out = (tensor ? Bbf : Abf) + ((size_t)b * NN + n0) * NC + c0;

  __shared__ float tile[64][65];
  int tr = threadIdx.x >> 6, tc = threadIdx.x & 63;
  #pragma unroll
  for (int i = 0; i < 16; ++i) {
    int c = i * 4 + tr;
    tile[c][tc] = in[(size_t)c * NN + tc];
  }
  __syncthreads();
  #pragma unroll
  for (int i = 0; i < 16; ++i) {
    int n = i * 4 + tr;
    out[(size_t)n * NC + tc] = f2bf(tile[tc][n]);
  }
}

// ---------------- fused GEMM(+hinge)+corr kernel ----------------
// blocks [0,6000): GEMM 160(n)x96(m), 4 waves 2x2, wave 80x48 = 5x3 frags 16x16x32
//                  K=256 in 8 chunks BK=32; 3 LDS bufs, counted vmcnt(4)
// blocks [6000,10800): sparse mask correction (4 waves = 4 (b,n) items)
#define BM 160
#define BN 96
#define BK 32

#define STAGE(kb, LA, LB) do {                                                        \
    _Pragma("unroll")                                                                 \
    for (int i_ = 0; i_ < 4; ++i_) {                                                  \
      if (inA_[i_])                                                                   \
        __builtin_amdgcn_global_load_lds(                                             \
            (const __attribute__((address_space(1))) uint32_t*)(gsrc_[i_] + (kb) * BK), \
            (__attribute__((address_space(3))) uint32_t*)(&LA[ldso_[i_]]), 16, 0, 0); \
      else                                                                            \
        __builtin_amdgcn_global_load_lds(                                             \
            (const __attribute__((address_space(1))) uint32_t*)(gsrc_[i_] + (kb) * BK), \
            (__attribute__((address_space(3))) uint32_t*)(&LB[ldso_[i_]]), 16, 0, 0); \
    }                                                                                 \
  } while (0)

#define COMPUTE(LA, LB) do {                                                          \
    bf16x8 af_[5], bf_[3];                                                            \
    _Pragma("unroll")                                                                 \
    for (int i_ = 0; i_ < 5; ++i_) af_[i_] = *(const bf16x8*)&LA[aoff_[i_]];          \
    _Pragma("unroll")                                                                 \
    for (int j_ = 0; j_ < 3; ++j_) bf_[j_] = *(const bf16x8*)&LB[boff_[j_]];          \
    __builtin_amdgcn_s_setprio(1);                                                    \
    _Pragma("unroll")                                                                 \
    for (int i_ = 0; i_ < 5; ++i_)                                                    \
      _Pragma("unroll")                                                               \
      for (int j_ = 0; j_ < 3; ++j_)                                                  \
        acc[i_][j_] = __builtin_amdgcn_mfma_f32_16x16x32_bf16(af_[i_], bf_[j_],       \
                                                              acc[i_][j_], 0, 0, 0);  \
    __builtin_amdgcn_s_setprio(0);                                                    \
  } while (0)

// counted-vmcnt wait + raw barrier; memory clobber + sched fence (rule #18)
#define WAITV_BAR(N) do {                                              \
    asm volatile("s_waitcnt vmcnt(" #N ")" ::: "memory");              \
    __builtin_amdgcn_sched_barrier(0);                                 \
    __builtin_amdgcn_s_barrier();                                      \
    __builtin_amdgcn_sched_barrier(0);                                 \
  } while (0)

__global__ __launch_bounds__(256, 3) void fused_kernel(
    const unsigned short* __restrict__ Abf, const unsigned short* __restrict__ Bbf,
    const float* __restrict__ H,
    float* __restrict__ gemmbuf, float* __restrict__ corrbuf) {
  __shared__ unsigned short la0[BM * BK], la1[BM * BK], la2[BM * BK];
  __shared__ unsigned short lb0[BN * BK], lb1[BN * BK], lb2[BN * BK];
  __shared__ float red[4];

  int bid = blockIdx.x;
  int tid = threadIdx.x;
  int w = tid >> 6, l = tid & 63;

  if (bid >= NGEMM) {
    // ================= corr path =================
    int cb  = bid - NGEMM;                 // 0..4799
    int gid = cb * 4 + w;                  // 0..19199
    int b = gid / NN, n = gid % NN;
    int gi = n / NW, gj = n % NW;
    float x = gj * 8.0f + 4.0f, y = gi * 8.0f + 4.0f;
    const float* h = H + b * 9;
    float inv = 1.0f / (h[6] * x + h[7] * y + h[8]);
    float wx = (h[0] * x + h[1] * y + h[2]) * inv;
    float wy = (h[3] * x + h[4] * y + h[5]) * inv;

    const uint2 av = *(const uint2*)(Abf + (size_t)(b * NN + n) * NC + l * 4);
    float a0 = __uint_as_float(av.x << 16);
    float a1 = __uint_as_float(av.x & 0xffff0000u);
    float a2 = __uint_as_float(av.y << 16);
    float a3 = __uint_as_float(av.y & 0xffff0000u);

    float fy = fminf(fmaxf((wy - 4.0f) * 0.125f, -2.0f), (float)NH + 1.0f);
    float fx = fminf(fmaxf((wx - 4.0f) * 0.125f, -2.0f), (float)NW + 1.0f);
    int i0 = (int)floorf(fy), j0 = (int)floorf(fx);

    bool  val[4];
    float dot[4];
    #pragma unroll
    for (int c = 0; c < 4; ++c) {
      int im = i0 + (c >> 1), jm = j0 + (c & 1);
      float dx = wx - (jm * 8.0f + 4.0f);
      float dy = wy - (im * 8.0f + 4.0f);
      bool v = (im >= 0) & (im < NH) & (jm >= 0) & (jm < NW) &
               (dx * dx + dy * dy <= THR2);
      val[c] = v;
      int m = v ? (im * NW + jm) : 0;
      const uint2 bv = *(const uint2*)(Bbf + (size_t)(b * NN + m) * NC + l * 4);
      dot[c] = a0 * __uint_as_float(bv.x << 16)
             + a1 * __uint_as_float(bv.x & 0xffff0000u)
             + a2 * __uint_as_float(bv.y << 16)
             + a3 * __uint_as_float(bv.y & 0xffff0000u);
    }
    #pragma unroll
    for (int off = 32; off > 0; off >>= 1) {
      dot[0] += __shfl_xor(dot[0], off);
      dot[1] += __shfl_xor(dot[1], off);
      dot[2] += __shfl_xor(dot[2], off);
      dot[3] += __shfl_xor(dot[3], off);
    }
    float corr = 0.0f;
    #pragma unroll
    for (int c = 0; c < 4; ++c)
      if (val[c])
        corr += fmaxf(M_POS - dot[c], 0.0f) - fmaxf(dot[c] - M_NEG, 0.0f);
    if (l == 0) red[w] = corr;
    __syncthreads();
    if (tid == 0) corrbuf[cb] = red[0] + red[1] + red[2] + red[3];
    return;
  }

  // ================= GEMM path =================
  // XCD-aware bijective swizzle over the 6000 gemm blocks
  int nb = (bid & 7) * 750 + (bid >> 3);
  int b = nb / 1500; int r = nb % 1500;
  int tn = r / 50, tm = r % 50;
  int n0 = tn * BM, m0 = tm * BN;
  int wr = w >> 1, wc = w & 1;

  const unsigned short* Ab = Abf + (size_t)b * NN * NC;
  const unsigned short* Bb = Bbf + (size_t)b * NN * NC;

  // hoisted staging addresses (loop-invariant; kb*64B folds into imm offset)
  bool inA_[4]; const unsigned short* gsrc_[4]; int ldso_[4];
  #pragma unroll
  for (int i = 0; i < 4; ++i) {
    int base = w * 256 + i * 64;
    int cid = base + l;
    if (base < 640) {
      int row = cid >> 2, col = cid & 3;
      int scol = col ^ ((row >> 1) & 3);
      inA_[i] = true;
      gsrc_[i] = Ab + (size_t)(n0 + row) * NC + scol * 8;
      ldso_[i] = base * 8;
    } else {
      int cid2 = cid - 640;
      int row = cid2 >> 2, col = cid2 & 3;
      int scol = col ^ ((row >> 1) & 3);
      inA_[i] = false;
      gsrc_[i] = Bb + (size_t)(m0 + row) * NC + scol * 8;
      ldso_[i] = (base - 640) * 8;
    }
  }
  // hoisted LDS fragment offsets (same involution on READ)
  int aoff_[5], boff_[3];
  {
    int c_ = l >> 4;
    #pragma unroll
    for (int i = 0; i < 5; ++i) {
      int ra = wr * 80 + i * 16 + (l & 15);
      aoff_[i] = ra * 32 + (c_ ^ ((ra >> 1) & 3)) * 8;
    }
    #pragma unroll
    for (int j = 0; j < 3; ++j) {
      int rb = wc * 48 + j * 16 + (l & 15);
      boff_[j] = rb * 32 + (c_ ^ ((rb >> 1) & 3)) * 8;
    }
  }

  f32x4 acc[5][3];
  #pragma unroll
  for (int i = 0; i < 5; ++i)
    #pragma unroll
    for (int j = 0; j < 3; ++j)
      acc[i][j] = (f32x4){0.f, 0.f, 0.f, 0.f};

  STAGE(0, la0, lb0);
  STAGE(1, la1, lb1);
  WAITV_BAR(4);                                    // chunk 0 landed
  STAGE(2, la2, lb2); COMPUTE(la0, lb0); WAITV_BAR(4);
  STAGE(3, la0, lb0); COMPUTE(la1, lb1); WAITV_BAR(4);
  STAGE(4, la1, lb1); COMPUTE(la2, lb2); WAITV_BAR(4);
  STAGE(5, la2, lb2); COMPUTE(la0, lb0); WAITV_BAR(4);
  STAGE(6, la0, lb0); COMPUTE(la1, lb1); WAITV_BAR(4);
  STAGE(7, la1, lb1); COMPUTE(la2, lb2); WAITV_BAR(4);
  COMPUTE(la0, lb0);  WAITV_BAR(0);                // drain chunk 7
  COMPUTE(la1, lb1);

  // epilogue: negative-branch hinge only (mask handled by corr path)
  float lsum = 0.0f;
  #pragma unroll
  for (int i = 0; i < 5; ++i)
    #pragma unroll
    for (int j = 0; j < 3; ++j)
      #pragma unroll
      for (int q = 0; q < 4; ++q)
        lsum += fmaxf(acc[i][j][q] - M_NEG, 0.0f);

  #pragma unroll
  for (int off = 32; off > 0; off >>= 1)
    lsum += __shfl_xor(lsum, off);
  if (l == 0) red[w] = lsum;
  __syncthreads();
  if (tid == 0)
    gemmbuf[nb] = red[0] + red[1] + red[2] + red[3];
}

// ---------------- final reduction over all partials ----------------
__global__ void finalize_kernel(const float* __restrict__ parts, float* __restrict__ out) {
  float v = 0.0f;
  for (int i = threadIdx.x; i < NPART; i += 1024)
    v += parts[i];
  #pragma unroll
  for (int off = 32; off > 0; off >>= 1)
    v += __shfl_xor(v, off);
  __shared__ float red[16];
  if ((threadIdx.x & 63) == 0) red[threadIdx.x >> 6] = v;
  __syncthreads();
  if (threadIdx.x == 0) {
    float s = 0.0f;
    #pragma unroll
    for (int i = 0; i < 16; ++i) s += red[i];
    out[0] = s * (1.0f / ((float)NB * (float)NN * (float)NN));
  }
}

extern "C" void kernel_launch(void* const* d_in, const int* in_sizes, int n_in,
                              void* d_out, int out_size, void* d_ws, size_t ws_size,
                              hipStream_t stream) {
  const float* da = (const float*)d_in[0];
  const float* db = (const float*)d_in[1];
  const float* H  = (const float*)d_in[2];
  // d_in[3] = valid_mask (all ones, unused by the reference math)

  char* ws = (char*)d_ws;
  float* gemmbuf = (float*)ws;                    // 6000 floats
  float* corrbuf = (float*)(ws + CORR_OFF);       // 4800 floats (contiguous after)
  unsigned short* Abf = (unsigned short*)(ws + ABF_OFF);
  unsigned short* Bbf = (unsigned short*)(ws + BBF_OFF);

  tconv_kernel<<<2400, 256, 0, stream>>>(da, db, Abf, Bbf);
  fused_kernel<<<NGEMM + NCORR, 256, 0, stream>>>(Abf, Bbf, H, gemmbuf, corrbuf);
  finalize_kernel<<<1, 1024, 0, stream>>>(gemmbuf, (float*)d_out);
}